// Round 1
// baseline (496.326 us; speedup 1.0000x reference)
//
#include <hip/hip_runtime.h>
#include <stdint.h>

#define T_LEN 1024
#define NSTATE 32

// Tree-reduce 16 candidates (this lane's half) with first-index tie-break,
// then combine across the two 32-lane halves (lower i preferred on ties).
// Matches jnp.argmax first-occurrence semantics exactly.
__device__ __forceinline__ void argmax32(const float v[16], int half,
                                         float& outv, int& outi)
{
    float v8[8]; int i8[8];
#pragma unroll
    for (int k = 0; k < 8; ++k) {
        bool c = v[2*k] >= v[2*k+1];
        v8[k] = fmaxf(v[2*k], v[2*k+1]);
        i8[k] = c ? 2*k : 2*k+1;
    }
    float v4[4]; int i4[4];
#pragma unroll
    for (int k = 0; k < 4; ++k) {
        bool c = v8[2*k] >= v8[2*k+1];
        v4[k] = fmaxf(v8[2*k], v8[2*k+1]);
        i4[k] = c ? i8[2*k] : i8[2*k+1];
    }
    float v2[2]; int i2[2];
#pragma unroll
    for (int k = 0; k < 2; ++k) {
        bool c = v4[2*k] >= v4[2*k+1];
        v2[k] = fmaxf(v4[2*k], v4[2*k+1]);
        i2[k] = c ? i4[2*k] : i4[2*k+1];
    }
    bool c1 = v2[0] >= v2[1];
    float v1 = fmaxf(v2[0], v2[1]);
    int i1 = c1 ? i2[0] : i2[1];
    int gi = half * 16 + i1;

    // cross-half combine (lane ^ 32); prefer smaller global index on ties
    float ov  = __shfl_xor(v1, 32);
    int   ogi = __shfl_xor(gi, 32);
    bool tm = (v1 > ov) || ((v1 == ov) && (gi < ogi));
    outv = tm ? v1 : ov;
    outi = tm ? gi : ogi;
}

__launch_bounds__(64)
__global__ void viterbi_kernel(const float* __restrict__ logits,
                               const float* __restrict__ trans,
                               const int* __restrict__ seqlen,
                               int* __restrict__ out)
{
    const int b    = blockIdx.x;
    const int lane = threadIdx.x;   // 0..63
    const int half = lane >> 5;     // i-half this lane reduces
    const int j    = lane & 31;     // output column

    __shared__ __align__(16) float   st[NSTATE];          // state vector
    __shared__ uint8_t bp[T_LEN * NSTATE];                 // backptrs t=1..L-1
    __shared__ uint8_t Farr[32 * 32];                      // chunk functions
    __shared__ uint8_t earr[32];                           // chunk entry tags
    __shared__ __align__(16) int pred[T_LEN];              // output row

    int L = seqlen[b];
    if (L < 0) L = 0;
    if (L > 1023) L = 1023;   // randint(0,T) guarantees this anyway

    // transitions column j, rows half*16 .. half*16+15 (kept in registers)
    float tr[16];
#pragma unroll
    for (int k = 0; k < 16; ++k)
        tr[k] = trans[(half * 16 + k) * NSTATE + j];

    const float* lg = logits + (size_t)b * T_LEN * NSTATE;

    // init: state = logits[b,0,:]
    st[j] = lg[j];               // lanes j and j+32 write the same value
    __syncthreads();

    const float4* st4 = reinterpret_cast<const float4*>(st);
    float pre = lg[NSTATE + j];  // prefetch logits[b,1,j] (always in bounds)

    // ---------------- forward ----------------
    for (int t = 1; t < L; ++t) {
        float4 q0 = st4[half*4 + 0];
        float4 q1 = st4[half*4 + 1];
        float4 q2 = st4[half*4 + 2];
        float4 q3 = st4[half*4 + 3];
        float lgt = pre;
        pre = lg[(t + 1) * NSTATE + j];   // t+1 <= 1023, in bounds

        float v[16];
        v[0]=q0.x+tr[0];  v[1]=q0.y+tr[1];  v[2]=q0.z+tr[2];  v[3]=q0.w+tr[3];
        v[4]=q1.x+tr[4];  v[5]=q1.y+tr[5];  v[6]=q1.z+tr[6];  v[7]=q1.w+tr[7];
        v[8]=q2.x+tr[8];  v[9]=q2.y+tr[9];  v[10]=q2.z+tr[10];v[11]=q2.w+tr[11];
        v[12]=q3.x+tr[12];v[13]=q3.y+tr[13];v[14]=q3.z+tr[14];v[15]=q3.w+tr[15];

        float wv; int wi;
        argmax32(v, half, wv, wi);

        float ns = wv + lgt;              // exact same add order as reference
        st[j] = ns;
        bp[t * NSTATE + j] = (uint8_t)wi;
        __syncthreads();
    }

    // ---------------- last_tag = argmax(final state) ----------------
    {
        float4 q0 = st4[half*4 + 0];
        float4 q1 = st4[half*4 + 1];
        float4 q2 = st4[half*4 + 2];
        float4 q3 = st4[half*4 + 3];
        float v[16] = {q0.x,q0.y,q0.z,q0.w, q1.x,q1.y,q1.z,q1.w,
                       q2.x,q2.y,q2.z,q2.w, q3.x,q3.y,q3.z,q3.w};
        float fv; int ft;
        argmax32(v, half, fv, ft);

        if (L >= 2) {
            // ---- phase 1: chunk functions, all 32 start states ----
            // lane handles chunk c = lane&31, starts j0 = (lane>>5)*16 + k
            const int c = lane & 31;
            const int j0base = (lane >> 5) * 16;
            int tags[16];
#pragma unroll
            for (int k = 0; k < 16; ++k) tags[k] = j0base + k;
            const int thi = c * 32 + 31;
            for (int s = 0; s < 32; ++s) {
                int t = thi - s;
                bool valid = (t >= 1) && (t <= L - 1);
                int tc = t < 1 ? 1 : (t > L - 1 ? L - 1 : t);
                int base = tc * NSTATE;
#pragma unroll
                for (int k = 0; k < 16; ++k) {
                    int nt = bp[base + tags[k]];
                    tags[k] = valid ? nt : tags[k];
                }
            }
#pragma unroll
            for (int k = 0; k < 16; ++k)
                Farr[c * 32 + j0base + k] = (uint8_t)tags[k];
            __syncthreads();

            // ---- phase 2: compose chunk entries (serial, 32 steps) ----
            if (lane == 0) {
                int e = ft;   // tag at t=1023 (identity steps keep last_tag)
                for (int c2 = 31; c2 >= 0; --c2) {
                    earr[c2] = (uint8_t)e;
                    e = Farr[c2 * 32 + e];
                }
            }
            __syncthreads();

            // ---- phase 3: re-walk chunks in parallel, emit pred ----
            if (lane < 32) {
                int tag = earr[lane];
                const int thi3 = lane * 32 + 31;
                for (int s = 0; s < 32; ++s) {
                    int t = thi3 - s;
                    pred[t] = (t < L) ? tag : 0;
                    bool valid = (t >= 1) && (t <= L - 1);
                    int tc = t < 1 ? 1 : (t > L - 1 ? L - 1 : t);
                    int nt = bp[tc * NSTATE + tag];
                    tag = valid ? nt : tag;
                }
            }
            __syncthreads();
        } else {
            // L == 0 or 1: row of zeros, except pred[0]=last_tag when L==1
#pragma unroll
            for (int r = 0; r < 16; ++r) pred[lane * 16 + r] = 0;
            __syncthreads();
            if (lane == 0 && L == 1) pred[0] = ft;
            __syncthreads();
        }
    }

    // ---------------- coalesced store ----------------
    int4* out4 = reinterpret_cast<int4*>(out + (size_t)b * T_LEN);
    const int4* p4 = reinterpret_cast<const int4*>(pred);
#pragma unroll
    for (int r = 0; r < 4; ++r)
        out4[r * 64 + lane] = p4[r * 64 + lane];
}

extern "C" void kernel_launch(void* const* d_in, const int* in_sizes, int n_in,
                              void* d_out, int out_size, void* d_ws, size_t ws_size,
                              hipStream_t stream) {
    const float* logits = (const float*)d_in[0];
    const float* trans  = (const float*)d_in[1];
    const int*   slen   = (const int*)d_in[2];
    int*         out    = (int*)d_out;
    const int B = in_sizes[2];   // 1024

    viterbi_kernel<<<dim3(B), dim3(64), 0, stream>>>(logits, trans, slen, out);
}

// Round 2
// 367.599 us; speedup vs baseline: 1.3502x; 1.3502x over previous
//
#include <hip/hip_runtime.h>
#include <stdint.h>

#define T_LEN 1024
#define NSTATE 32

__device__ __forceinline__ float max3f(float a, float b, float c) {
    return fmaxf(fmaxf(a, b), c);   // fuses to v_max3_f32
}
__device__ __forceinline__ int min3i(int a, int b, int c) {
    return min(min(a, b), c);       // fuses to v_min3_i32
}

__launch_bounds__(64)
__global__ void viterbi_kernel(const float* __restrict__ logits,
                               const float* __restrict__ trans,
                               const int* __restrict__ seqlen,
                               int* __restrict__ out)
{
    const int b    = blockIdx.x;
    const int lane = threadIdx.x;   // 0..63
    const int half = lane >> 5;     // which i-half this lane reduces
    const int j    = lane & 31;     // output column (state owned: lane j & j+32)

    __shared__ uint8_t bp[T_LEN * NSTATE];     // backptrs, t=1..L-1
    __shared__ uint8_t Farr[32 * 32];          // chunk functions
    __shared__ uint8_t earr[32];               // chunk entry tags
    __shared__ __align__(16) int pred[T_LEN];  // output row

    int L = seqlen[b];
    if (L < 0) L = 0;
    if (L > 1023) L = 1023;

    // transitions column j, rows half*16 .. half*16+15 (registers)
    const int h16 = half * 16;
    float tr[16];
#pragma unroll
    for (int k = 0; k < 16; ++k)
        tr[k] = trans[(h16 + k) * NSTATE + j];

    const float* lg = logits + (size_t)b * T_LEN * NSTATE;

    // state[j] lives in registers of lanes j and j+32
    float ns = lg[j];

    const int baddr = h16 * 4;   // ds_bpermute byte base for this half

    // one forward step: consumes logit value lgt for time t
    auto step = [&](int t, float lgt) {
        float v[16];
        int nsb = __float_as_int(ns);
#pragma unroll
        for (int k = 0; k < 16; ++k)
            v[k] = __int_as_float(__builtin_amdgcn_ds_bpermute(baddr + 4 * k, nsb)) + tr[k];

        // half-max via max3 tree (value only — the critical path)
        float a0 = max3f(v[0],  v[1],  v[2]);
        float a1 = max3f(v[3],  v[4],  v[5]);
        float a2 = max3f(v[6],  v[7],  v[8]);
        float a3 = max3f(v[9],  v[10], v[11]);
        float a4 = max3f(v[12], v[13], v[14]);
        float b0 = max3f(a0, a1, v[15]);
        float b1 = max3f(a2, a3, a4);
        float hm = fmaxf(b0, b1);
        float gm = fmaxf(hm, __shfl_xor(hm, 32));   // global max over 32 candidates

        ns = gm + lgt;   // critical recurrence (same add order as reference)

        // argmax index — off critical path; exact first-occurrence tie-break
        int ix[16];
#pragma unroll
        for (int k = 0; k < 16; ++k)
            ix[k] = (v[k] == gm) ? (h16 + k) : 99;
        int c0 = min3i(ix[0],  ix[1],  ix[2]);
        int c1 = min3i(ix[3],  ix[4],  ix[5]);
        int c2 = min3i(ix[6],  ix[7],  ix[8]);
        int c3 = min3i(ix[9],  ix[10], ix[11]);
        int c4 = min3i(ix[12], ix[13], ix[14]);
        int d0 = min3i(c0, c1, ix[15]);
        int d1 = min3i(c2, c3, c4);
        int idx = min(d0, d1);
        idx = min(idx, __shfl_xor(idx, 32));        // prefer smaller global i
        if (lane < 32) bp[t * NSTATE + j] = (uint8_t)idx;
    };

    // ---------------- forward (no barriers: single wave) ----------------
    if (L >= 2) {
        float pre[4];
#pragma unroll
        for (int d = 0; d < 4; ++d) {
            int tp = 1 + d; if (tp > 1023) tp = 1023;
            pre[d] = lg[tp * NSTATE + j];
        }
        int t = 1;
        for (; t + 4 <= L; t += 4) {
            step(t + 0, pre[0]); { int tp = t + 4; if (tp > 1023) tp = 1023; pre[0] = lg[tp * NSTATE + j]; }
            step(t + 1, pre[1]); { int tp = t + 5; if (tp > 1023) tp = 1023; pre[1] = lg[tp * NSTATE + j]; }
            step(t + 2, pre[2]); { int tp = t + 6; if (tp > 1023) tp = 1023; pre[2] = lg[tp * NSTATE + j]; }
            step(t + 3, pre[3]); { int tp = t + 7; if (tp > 1023) tp = 1023; pre[3] = lg[tp * NSTATE + j]; }
        }
        for (int k = 0; t < L; ++t, ++k) step(t, pre[k]);
    }

    // ---------------- last_tag = argmax(final state) via butterfly ----------------
    float m = ns;
#pragma unroll
    for (int d = 1; d < 32; d <<= 1) m = fmaxf(m, __shfl_xor(m, d));
    int ii = (ns == m) ? j : 99;
#pragma unroll
    for (int d = 1; d < 32; d <<= 1) ii = min(ii, __shfl_xor(ii, d));
    const int ft = ii;   // last tag (identical in all lanes)

    __syncthreads();   // bp visible for backtrace (once; cheap)

    if (L >= 2) {
        // ---- phase 1: chunk functions, all 32 start states ----
        const int c = lane & 31;
        const int j0base = (lane >> 5) * 16;
        int tags[16];
#pragma unroll
        for (int k = 0; k < 16; ++k) tags[k] = j0base + k;
        const int thi = c * 32 + 31;
        for (int s = 0; s < 32; ++s) {
            int t = thi - s;
            bool valid = (t >= 1) && (t <= L - 1);
            int tc = t < 1 ? 1 : (t > L - 1 ? L - 1 : t);
            int base = tc * NSTATE;
#pragma unroll
            for (int k = 0; k < 16; ++k) {
                int nt = bp[base + tags[k]];
                tags[k] = valid ? nt : tags[k];
            }
        }
#pragma unroll
        for (int k = 0; k < 16; ++k)
            Farr[c * 32 + j0base + k] = (uint8_t)tags[k];
        __syncthreads();

        // ---- phase 2: compose chunk entries (serial, 32 steps) ----
        if (lane == 0) {
            int e = ft;
            for (int c2 = 31; c2 >= 0; --c2) {
                earr[c2] = (uint8_t)e;
                e = Farr[c2 * 32 + e];
            }
        }
        __syncthreads();

        // ---- phase 3: re-walk chunks in parallel, emit pred ----
        if (lane < 32) {
            int tag = earr[lane];
            const int thi3 = lane * 32 + 31;
            for (int s = 0; s < 32; ++s) {
                int t = thi3 - s;
                pred[t] = (t < L) ? tag : 0;
                bool valid = (t >= 1) && (t <= L - 1);
                int tc = t < 1 ? 1 : (t > L - 1 ? L - 1 : t);
                int nt = bp[tc * NSTATE + tag];
                tag = valid ? nt : tag;
            }
        }
        __syncthreads();
    } else {
        // L == 0 or 1
#pragma unroll
        for (int r = 0; r < 16; ++r) pred[lane * 16 + r] = 0;
        __syncthreads();
        if (lane == 0 && L == 1) pred[0] = ft;
        __syncthreads();
    }

    // ---------------- coalesced store ----------------
    int4* out4 = reinterpret_cast<int4*>(out + (size_t)b * T_LEN);
    const int4* p4 = reinterpret_cast<const int4*>(pred);
#pragma unroll
    for (int r = 0; r < 4; ++r)
        out4[r * 64 + lane] = p4[r * 64 + lane];
}

extern "C" void kernel_launch(void* const* d_in, const int* in_sizes, int n_in,
                              void* d_out, int out_size, void* d_ws, size_t ws_size,
                              hipStream_t stream) {
    const float* logits = (const float*)d_in[0];
    const float* trans  = (const float*)d_in[1];
    const int*   slen   = (const int*)d_in[2];
    int*         out    = (int*)d_out;
    const int B = in_sizes[2];   // 1024

    viterbi_kernel<<<dim3(B), dim3(64), 0, stream>>>(logits, trans, slen, out);
}

// Round 3
// 266.803 us; speedup vs baseline: 1.8603x; 1.3778x over previous
//
#include <hip/hip_runtime.h>
#include <stdint.h>

#define T_LEN 1024
#define NSTATE 32

typedef int v2i __attribute__((ext_vector_type(2)));

__device__ __forceinline__ float max3f(float a, float b, float c) {
    return fmaxf(fmaxf(a, b), c);   // v_max3_f32
}
__device__ __forceinline__ int min3i(int a, int b, int c) {
    return min(min(a, b), c);       // v_min3_i32
}

// Cross-half (lane <-> lane^32) combine on the VALU pipe via permlane32_swap.
// Robust to either swap-direction semantics: per lane, {r[0], r[1]} is always
// {own value, partner value}.
__device__ __forceinline__ float xhalf_max(float x) {
    v2i r = __builtin_amdgcn_permlane32_swap(__float_as_int(x), __float_as_int(x), false, false);
    return fmaxf(__int_as_float(r[0]), __int_as_float(r[1]));
}
__device__ __forceinline__ int xhalf_min(int x) {
    v2i r = __builtin_amdgcn_permlane32_swap(x, x, false, false);
    return min(r[0], r[1]);
}

__launch_bounds__(64)
__global__ void viterbi_kernel(const float* __restrict__ logits,
                               const float* __restrict__ trans,
                               const int* __restrict__ seqlen,
                               int* __restrict__ out)
{
    const int lane = threadIdx.x;   // 0..63
    const int half = lane >> 5;     // which i-half this lane reduces
    const int j    = lane & 31;     // output column (lanes j and j+32 duplicate)

    __shared__ __align__(16) float st[NSTATE];  // state vector (LDS broadcast row)
    __shared__ uint8_t bp[T_LEN * NSTATE];      // backptrs, t=1..L-1
    __shared__ uint8_t Farr[32 * 32];           // chunk functions
    __shared__ uint8_t earr[32];                // chunk entry tags
    __shared__ __align__(16) int pred[T_LEN];   // output row

    int L = seqlen[blockIdx.x];
    if (L < 0) L = 0;
    if (L > 1023) L = 1023;

    const int h16 = half * 16;
    float tr[16];
#pragma unroll
    for (int k = 0; k < 16; ++k)
        tr[k] = trans[(h16 + k) * NSTATE + j];

    const float* lg = logits + (size_t)blockIdx.x * T_LEN * NSTATE;

    // state[j] lives in lanes j and j+32 (duplicated)
    float ns = lg[j];

    const float4* st4 = reinterpret_cast<const float4*>(st);

    // one forward step: consumes logit value lgt for time t
    auto step = [&](int t, float lgt) {
        st[j] = ns;                      // 1 ds_write_b32 (dup write, benign)
        float4 q0 = st4[half * 4 + 0];   // 4 broadcast ds_read_b128
        float4 q1 = st4[half * 4 + 1];
        float4 q2 = st4[half * 4 + 2];
        float4 q3 = st4[half * 4 + 3];

        float v[16];
        v[0]=q0.x+tr[0];  v[1]=q0.y+tr[1];  v[2]=q0.z+tr[2];  v[3]=q0.w+tr[3];
        v[4]=q1.x+tr[4];  v[5]=q1.y+tr[5];  v[6]=q1.z+tr[6];  v[7]=q1.w+tr[7];
        v[8]=q2.x+tr[8];  v[9]=q2.y+tr[9];  v[10]=q2.z+tr[10];v[11]=q2.w+tr[11];
        v[12]=q3.x+tr[12];v[13]=q3.y+tr[13];v[14]=q3.z+tr[14];v[15]=q3.w+tr[15];

        // half-max via max3 tree (value critical path)
        float a0 = max3f(v[0],  v[1],  v[2]);
        float a1 = max3f(v[3],  v[4],  v[5]);
        float a2 = max3f(v[6],  v[7],  v[8]);
        float a3 = max3f(v[9],  v[10], v[11]);
        float a4 = max3f(v[12], v[13], v[14]);
        float b0 = max3f(a0, a1, v[15]);
        float b1 = max3f(a2, a3, a4);
        float hm = fmaxf(b0, b1);
        float gm = xhalf_max(hm);        // VALU-pipe cross-half combine

        ns = gm + lgt;                   // same add order as reference

        // argmax index — off critical path; exact first-occurrence tie-break.
        // "none" sentinel = 64 (inline constant, > any index 0..31)
        int ix[16];
#pragma unroll
        for (int k = 0; k < 16; ++k)
            ix[k] = (v[k] == gm) ? (h16 + k) : 64;
        int c0 = min3i(ix[0],  ix[1],  ix[2]);
        int c1 = min3i(ix[3],  ix[4],  ix[5]);
        int c2 = min3i(ix[6],  ix[7],  ix[8]);
        int c3 = min3i(ix[9],  ix[10], ix[11]);
        int c4 = min3i(ix[12], ix[13], ix[14]);
        int d0 = min3i(c0, c1, ix[15]);
        int d1 = min3i(c2, c3, c4);
        int ih = min(d0, d1);
        int idx = xhalf_min(ih);         // VALU-pipe cross-half min-index

        bp[t * NSTATE + j] = (uint8_t)idx;   // dup byte write, same value
    };

    // ---------------- forward (single wave: no barriers) ----------------
    if (L >= 2) {
        float pre[4];
#pragma unroll
        for (int d = 0; d < 4; ++d) {
            int tp = 1 + d; if (tp > 1023) tp = 1023;
            pre[d] = lg[tp * NSTATE + j];
        }
        int t = 1;
        for (; t + 4 <= L; t += 4) {
            step(t + 0, pre[0]); { int tp = t + 4; if (tp > 1023) tp = 1023; pre[0] = lg[tp * NSTATE + j]; }
            step(t + 1, pre[1]); { int tp = t + 5; if (tp > 1023) tp = 1023; pre[1] = lg[tp * NSTATE + j]; }
            step(t + 2, pre[2]); { int tp = t + 6; if (tp > 1023) tp = 1023; pre[2] = lg[tp * NSTATE + j]; }
            step(t + 3, pre[3]); { int tp = t + 7; if (tp > 1023) tp = 1023; pre[3] = lg[tp * NSTATE + j]; }
        }
        for (int k = 0; t < L; ++t, ++k) step(t, pre[k]);
    }

    // ---------------- last_tag = argmax(final state) ----------------
    float m = ns;
#pragma unroll
    for (int d = 1; d < 32; d <<= 1) m = fmaxf(m, __shfl_xor(m, d));
    int ii = (ns == m) ? j : 64;
#pragma unroll
    for (int d = 1; d < 32; d <<= 1) ii = min(ii, __shfl_xor(ii, d));
    const int ft = ii;   // last tag (identical in all lanes)

    __syncthreads();   // bp visible (same wave anyway; cheap, once)

    if (L >= 2) {
        // ---- phase 1: chunk functions, all 32 start states ----
        const int c = lane & 31;
        const int j0base = (lane >> 5) * 16;
        int tags[16];
#pragma unroll
        for (int k = 0; k < 16; ++k) tags[k] = j0base + k;
        const int thi = c * 32 + 31;
        for (int s = 0; s < 32; ++s) {
            int t = thi - s;
            bool valid = (t >= 1) && (t <= L - 1);
            int tc = t < 1 ? 1 : (t > L - 1 ? L - 1 : t);
            int base = tc * NSTATE;
#pragma unroll
            for (int k = 0; k < 16; ++k) {
                int nt = bp[base + tags[k]];
                tags[k] = valid ? nt : tags[k];
            }
        }
#pragma unroll
        for (int k = 0; k < 16; ++k)
            Farr[c * 32 + j0base + k] = (uint8_t)tags[k];
        __syncthreads();

        // ---- phase 2: compose chunk entries (serial, 32 steps) ----
        if (lane == 0) {
            int e = ft;
            for (int c2 = 31; c2 >= 0; --c2) {
                earr[c2] = (uint8_t)e;
                e = Farr[c2 * 32 + e];
            }
        }
        __syncthreads();

        // ---- phase 3: re-walk chunks in parallel, emit pred ----
        if (lane < 32) {
            int tag = earr[lane];
            const int thi3 = lane * 32 + 31;
            for (int s = 0; s < 32; ++s) {
                int t = thi3 - s;
                pred[t] = (t < L) ? tag : 0;
                bool valid = (t >= 1) && (t <= L - 1);
                int tc = t < 1 ? 1 : (t > L - 1 ? L - 1 : t);
                int nt = bp[tc * NSTATE + tag];
                tag = valid ? nt : tag;
            }
        }
        __syncthreads();
    } else {
        // L == 0 or 1
#pragma unroll
        for (int r = 0; r < 16; ++r) pred[lane * 16 + r] = 0;
        __syncthreads();
        if (lane == 0 && L == 1) pred[0] = ft;
        __syncthreads();
    }

    // ---------------- coalesced store ----------------
    int4* out4 = reinterpret_cast<int4*>(out + (size_t)blockIdx.x * T_LEN);
    const int4* p4 = reinterpret_cast<const int4*>(pred);
#pragma unroll
    for (int r = 0; r < 4; ++r)
        out4[r * 64 + lane] = p4[r * 64 + lane];
}

extern "C" void kernel_launch(void* const* d_in, const int* in_sizes, int n_in,
                              void* d_out, int out_size, void* d_ws, size_t ws_size,
                              hipStream_t stream) {
    const float* logits = (const float*)d_in[0];
    const float* trans  = (const float*)d_in[1];
    const int*   slen   = (const int*)d_in[2];
    int*         out    = (int*)d_out;
    const int B = in_sizes[2];   // 1024

    viterbi_kernel<<<dim3(B), dim3(64), 0, stream>>>(logits, trans, slen, out);
}